// Round 5
// baseline (275.447 us; speedup 1.0000x reference)
//
#include <hip/hip_runtime.h>

// CRF forward as a segmented MATRIX scan on MFMA.
//   step matrix  A_t = diag(e^{h_t}) * Et,  Et = e^{trans} (elementwise, NEG -> 0)
//   segment s:   P_s = A_{last} ... A_{first}   (32x32, exp domain, pow2-renormed)
//   masking: step t>=len is identity -> per-wave loop bound, no per-step select
//   answer_b = ln2 * (sum_s R_s + renorms + log2( sum_i e^{trans[END][i]} * (P_3 P_2 P_1 P_0 onehot_START)[i] ))
// Scan: one wave per (batch, segment); 2 MFMAs per step; D->B relayout via
// 8 v_cvt_pk_bf16_f32 + 4 v_permlane32_swap_b32 (no LDS).

#define T_LEN 512
#define B_SZ  2048
#define K_SZ  32
#define TBK   65536
#define SEGS  4
#define SEG_T 128
#define START_S 29
#define END_S   30
#define L2E 1.4426950408889634f
#define LN2 0.6931471805599453f

#if defined(__has_builtin) && __has_builtin(__builtin_amdgcn_exp2f)
#define EXP2F(x) __builtin_amdgcn_exp2f(x)
#else
#define EXP2F(x) exp2f(x)
#endif
#if defined(__has_builtin) && __has_builtin(__builtin_amdgcn_logf)
#define LOG2F(x) __builtin_amdgcn_logf(x)
#else
#define LOG2F(x) log2f(x)
#endif

typedef float f32x16 __attribute__((ext_vector_type(16)));
typedef short s16x8  __attribute__((ext_vector_type(8)));

__device__ __forceinline__ unsigned cvtpk(float lo, float hi) {
  unsigned r;
  asm("v_cvt_pk_bf16_f32 %0, %1, %2" : "=v"(r) : "v"(lo), "v"(hi));
  return r;
}
__device__ __forceinline__ void swap32(unsigned &a, unsigned &b) {
  // after: a[l<32]=a, a[l>=32]=b[l-32]; b[l<32]=a[l+32], b[l>=32]=b
  asm("v_permlane32_swap_b32 %0, %1" : "+v"(a), "+v"(b));
}
__device__ __forceinline__ s16x8 pack8(unsigned a0, unsigned a1, unsigned a2, unsigned a3) {
  union { unsigned u[4]; s16x8 v; } t;
  t.u[0] = a0; t.u[1] = a1; t.u[2] = a2; t.u[3] = a3;
  return t.v;
}

__global__ __launch_bounds__(256) void crf_seg(
    const float* __restrict__ hid, const float* __restrict__ msk,
    const float* __restrict__ trans,
    unsigned* __restrict__ Pws, int* __restrict__ Rws)
{
  const int tx  = threadIdx.x;
  const int l   = tx & 63;
  const int wid = blockIdx.x * 4 + (tx >> 6);
  const int b   = wid >> 2;
  const int seg = wid & 3;
  const int n   = l & 31;     // A-row / B-col / D-col for this lane
  const int h2  = l >> 5;     // k-half selector

  // Et fragment (f32): row n, cols h2*8+j (k=0..15 half) and 16+h2*8+j (k=16..31 half)
  float Et[16];
  #pragma unroll
  for (int j = 0; j < 8; ++j) Et[j]   = EXP2F(trans[n * K_SZ + h2 * 8 + j] * L2E);
  #pragma unroll
  for (int j = 0; j < 8; ++j) Et[8+j] = EXP2F(trans[n * K_SZ + 16 + h2 * 8 + j] * L2E);

  // steps this (b,seg) actually runs (mask is monotone t>=len)
  float m0 = msk[(size_t)(seg * SEG_T + l) * B_SZ + b];
  float m1 = msk[(size_t)(seg * SEG_T + 64 + l) * B_SZ + b];
  int nsteps = __popcll(__ballot(m0 == 0.0f)) + __popcll(__ballot(m1 == 0.0f));

  // B fragments = identity (bf16 1.0 = 0x3F80)
  auto idpk = [&](int k0) -> unsigned {
    unsigned lo = (k0     == n) ? 0x3F80u : 0u;
    unsigned hi = (k0 + 1 == n) ? 0x3F80u : 0u;
    return lo | (hi << 16);
  };
  unsigned B1q0 = idpk(h2*8+0), B1q1 = idpk(h2*8+2), B1q2 = idpk(h2*8+4), B1q3 = idpk(h2*8+6);
  unsigned B2q0 = idpk(16+h2*8+0), B2q1 = idpk(16+h2*8+2), B2q2 = idpk(16+h2*8+4), B2q3 = idpk(16+h2*8+6);

  // D = identity f32 (survives only if nsteps==0)
  f32x16 d;
  #pragma unroll
  for (int r = 0; r < 16; ++r) {
    int row = (r & 3) + 8 * (r >> 2) + 4 * h2;
    d[r] = (row == n) ? 1.0f : 0.0f;
  }

  const float* hp = hid + (size_t)b * K_SZ + n;
  const int t0g = seg * SEG_T;
  float hr0 = hp[(size_t)(t0g + 0) * TBK];
  float hr1 = hp[(size_t)(t0g + 1) * TBK];
  float hr2 = hp[(size_t)(t0g + 2) * TBK];
  float hr3 = hp[(size_t)(t0g + 3) * TBK];
  int Rr = 0;

  auto step = [&](float hv) {
    float ehf = EXP2F(hv * L2E);
    unsigned a0 = cvtpk(ehf * Et[0],  ehf * Et[1]);
    unsigned a1 = cvtpk(ehf * Et[2],  ehf * Et[3]);
    unsigned a2 = cvtpk(ehf * Et[4],  ehf * Et[5]);
    unsigned a3 = cvtpk(ehf * Et[6],  ehf * Et[7]);
    unsigned a4 = cvtpk(ehf * Et[8],  ehf * Et[9]);
    unsigned a5 = cvtpk(ehf * Et[10], ehf * Et[11]);
    unsigned a6 = cvtpk(ehf * Et[12], ehf * Et[13]);
    unsigned a7 = cvtpk(ehf * Et[14], ehf * Et[15]);
    f32x16 z = {0.0f};
    d = __builtin_amdgcn_mfma_f32_32x32x16_bf16(pack8(a0,a1,a2,a3), pack8(B1q0,B1q1,B1q2,B1q3), z, 0, 0, 0);
    d = __builtin_amdgcn_mfma_f32_32x32x16_bf16(pack8(a4,a5,a6,a7), pack8(B2q0,B2q1,B2q2,B2q3), d, 0, 0, 0);
  };
  auto renorm = [&]() {
    int ex = (int)((__float_as_uint(d[0]) >> 23) & 255) - 127;   // exponent of P[0][0] (lane0)
    int s  = __builtin_amdgcn_readfirstlane(ex);
    float sc = __uint_as_float((unsigned)(127 - s) << 23);       // exact 2^-s
    d *= sc;
    Rr += s;
  };
  auto toB = [&]() {
    unsigned c0 = cvtpk(d[0],  d[1]),  c1 = cvtpk(d[2],  d[3]);
    unsigned c2 = cvtpk(d[4],  d[5]),  c3 = cvtpk(d[6],  d[7]);
    swap32(c0, c2); swap32(c1, c3);
    B1q0 = c0; B1q1 = c1; B1q2 = c2; B1q3 = c3;
    unsigned e0 = cvtpk(d[8],  d[9]),  e1 = cvtpk(d[10], d[11]);
    unsigned e2 = cvtpk(d[12], d[13]), e3 = cvtpk(d[14], d[15]);
    swap32(e0, e2); swap32(e1, e3);
    B2q0 = e0; B2q1 = e1; B2q2 = e2; B2q3 = e3;
  };

  const int nfull = nsteps >> 2;
  const int rem   = nsteps & 3;
  int t = t0g;
  for (int c = 0; c < nfull; ++c) {
    float hu;
    int t4 = t + 4, t5 = t + 5, t6 = t + 6, t7 = t + 7;
    t4 = t4 < (T_LEN-1) ? t4 : (T_LEN-1);
    t5 = t5 < (T_LEN-1) ? t5 : (T_LEN-1);
    t6 = t6 < (T_LEN-1) ? t6 : (T_LEN-1);
    t7 = t7 < (T_LEN-1) ? t7 : (T_LEN-1);
    hu = hr0; hr0 = hp[(size_t)t4 * TBK]; step(hu); toB();
    hu = hr1; hr1 = hp[(size_t)t5 * TBK]; step(hu); toB();
    hu = hr2; hr2 = hp[(size_t)t6 * TBK]; step(hu); toB();
    hu = hr3; hr3 = hp[(size_t)t7 * TBK]; step(hu); renorm(); toB();
    t += 4;
  }
  if (rem > 0) {
    step(hr0);
    if (rem > 1) { toB(); step(hr1); }
    if (rem > 2) { toB(); step(hr2); }
    renorm();
  }

  // store P as bf16 rowpairs: u32 at [seg][b][rp][col], rp pairs rows (2rp,2rp+1)
  unsigned o0 = cvtpk(d[0],  d[1]);   // rows 0+4h2,1+4h2  -> rp 0+2h2
  unsigned o1 = cvtpk(d[2],  d[3]);   // rp 1+2h2
  unsigned o2 = cvtpk(d[4],  d[5]);   // rp 4+2h2
  unsigned o3 = cvtpk(d[6],  d[7]);   // rp 5+2h2
  unsigned o4 = cvtpk(d[8],  d[9]);   // rp 8+2h2
  unsigned o5 = cvtpk(d[10], d[11]);  // rp 9+2h2
  unsigned o6 = cvtpk(d[12], d[13]);  // rp 12+2h2
  unsigned o7 = cvtpk(d[14], d[15]);  // rp 13+2h2
  unsigned* base = Pws + (size_t)(seg * B_SZ + b) * 512 + n;
  base[(0  + 2*h2) * 32] = o0;
  base[(1  + 2*h2) * 32] = o1;
  base[(4  + 2*h2) * 32] = o2;
  base[(5  + 2*h2) * 32] = o3;
  base[(8  + 2*h2) * 32] = o4;
  base[(9  + 2*h2) * 32] = o5;
  base[(12 + 2*h2) * 32] = o6;
  base[(13 + 2*h2) * 32] = o7;
  if (l == 0) Rws[seg * B_SZ + b] = Rr;
}

__global__ __launch_bounds__(256) void crf_comb(
    const unsigned* __restrict__ Pws, const int* __restrict__ Rws,
    const float* __restrict__ trans, float* __restrict__ out)
{
  __shared__ float sm[8][32];
  const int tx = threadIdx.x;
  const int g  = tx >> 5;
  const int i  = tx & 31;          // output row
  const int b  = blockIdx.x * 8 + g;

  float v  = (i == START_S) ? 1.0f : 0.0f;
  float Rt = 0.0f;

  #pragma unroll
  for (int s = 0; s < SEGS; ++s) {
    const unsigned* pr = Pws + (size_t)(s * B_SZ + b) * 512 + (i >> 1) * 32;
    float w[32];
    #pragma unroll
    for (int c4 = 0; c4 < 8; ++c4) {
      uint4 u = *(const uint4*)(pr + c4 * 4);
      const bool hi = (i & 1);
      w[c4*4+0] = __uint_as_float(hi ? (u.x & 0xFFFF0000u) : (u.x << 16));
      w[c4*4+1] = __uint_as_float(hi ? (u.y & 0xFFFF0000u) : (u.y << 16));
      w[c4*4+2] = __uint_as_float(hi ? (u.z & 0xFFFF0000u) : (u.z << 16));
      w[c4*4+3] = __uint_as_float(hi ? (u.w & 0xFFFF0000u) : (u.w << 16));
    }
    sm[g][i] = v;                       // same-wave write->read, DS pipe in order
    float a0 = 0.f, a1 = 0.f, a2 = 0.f, a3 = 0.f;
    #pragma unroll
    for (int q = 0; q < 8; ++q) {
      float4 vv = *(const float4*)&sm[g][q * 4];
      a0 = fmaf(vv.x, w[q*4+0], a0);
      a1 = fmaf(vv.y, w[q*4+1], a1);
      a2 = fmaf(vv.z, w[q*4+2], a2);
      a3 = fmaf(vv.w, w[q*4+3], a3);
    }
    float acc = (a0 + a1) + (a2 + a3);
    float c0  = __shfl(acc, 0, 32);     // v[0] > 0 always
    int   ex  = (int)((__float_as_uint(c0) >> 23) & 255) - 127;
    float sc  = __uint_as_float((unsigned)(127 - ex) << 23);
    v   = acc * sc;
    Rt += (float)ex + (float)Rws[s * B_SZ + b];
  }

  float p = v * EXP2F(trans[END_S * K_SZ + i] * L2E);
  p += __shfl_xor(p, 1);
  p += __shfl_xor(p, 2);
  p += __shfl_xor(p, 4);
  p += __shfl_xor(p, 8);
  p += __shfl_xor(p, 16);
  if (i == 0) out[b] = (Rt + LOG2F(p)) * LN2;
}

extern "C" void kernel_launch(void* const* d_in, const int* in_sizes, int n_in,
                              void* d_out, int out_size, void* d_ws, size_t ws_size,
                              hipStream_t stream) {
  const float* hid   = (const float*)d_in[0];   // (512, 2048, 32) f32
  const float* msk   = (const float*)d_in[1];   // (512, 2048)     f32
  const float* trans = (const float*)d_in[2];   // (32, 32)        f32
  float* out = (float*)d_out;                   // (2048,)         f32

  // ws: P bf16-rowpair u32 [4][2048][512] = 16.8 MB, then R int [4][2048]
  unsigned* Pws = (unsigned*)d_ws;
  int*      Rws = (int*)((char*)d_ws + (size_t)SEGS * B_SZ * 512 * 4);

  crf_seg <<<dim3(B_SZ * SEGS / 4), dim3(256), 0, stream>>>(hid, msk, trans, Pws, Rws);
  crf_comb<<<dim3(B_SZ / 8),        dim3(256), 0, stream>>>(Pws, Rws, trans, out);
}